// Round 11
// baseline (447.342 us; speedup 1.0000x reference)
//
#include <hip/hip_runtime.h>

static inline int divup(long a, long b){ return (int)((a + b - 1) / b); }

typedef float f32x4 __attribute__((ext_vector_type(4)));

#define CAP    64      // padded fallback: slots per dst node
#define BSHIFT 9       // 512 nodes per bucket
#define BNODES 512
#define CAP_E  12288   // fixed per-bucket region (mean ~8163, 29+ sigma headroom)
#define PBLK   256     // partition blocks

// ---------------- utility ----------------

__global__ void k_zero32(unsigned* __restrict__ p, long n){
  long i = (long)blockIdx.x * blockDim.x + threadIdx.x;
  long st = (long)gridDim.x * blockDim.x;
  for (; i < n; i += st) p[i] = 0u;
}

// ---------------- prep: direct padded-bucket partition ----------------
__global__ __launch_bounds__(256) void k_part2(const int* __restrict__ src,
    const int* __restrict__ dst, int E, int per,
    int* __restrict__ curD, int* __restrict__ curS,
    unsigned* __restrict__ partD, int* __restrict__ partS)
{
  __shared__ int hD[256], hS[256];
  const int t = threadIdx.x;
  const int b0 = blockIdx.x * per, b1 = min(E, b0 + per);
  hD[t] = 0; hS[t] = 0;
  __syncthreads();
  for (int i = b0 + t; i < b1; i += 256){
    atomicAdd(&hD[dst[i] >> BSHIFT], 1);
    atomicAdd(&hS[src[i] >> BSHIFT], 1);
  }
  __syncthreads();
  { int c = hD[t]; hD[t] = c ? atomicAdd(&curD[t], c) : 0;
    c = hS[t];     hS[t] = c ? atomicAdd(&curS[t], c) : 0; }
  __syncthreads();
  for (int i = b0 + t; i < b1; i += 256){
    int s = src[i], d = dst[i];
    int bD = d >> BSHIFT;
    int p = atomicAdd(&hD[bD], 1);
    if (p < CAP_E)
      partD[(long)bD * CAP_E + p] = ((unsigned)(d & (BNODES - 1)) << 17) | (unsigned)s;
    int bS = s >> BSHIFT;
    int q = atomicAdd(&hS[bS], 1);
    if (q < CAP_E)
      partS[(long)bS * CAP_E + q] = s;
  }
}

// per-bucket LDS counting sort IN PLACE (csr overwrites partD) -> rowptr,
// degD; then degS histogram from partS. One block per bucket.
__global__ __launch_bounds__(256) void k_csr_degs(const int* __restrict__ curD,
    const int* __restrict__ curS, unsigned* __restrict__ partD,
    const int* __restrict__ partS, int* __restrict__ rowptr,
    int* __restrict__ degD, int* __restrict__ degS, int N)
{
  __shared__ unsigned ed[CAP_E];          // 48 KB
  __shared__ int cnt[BNODES], scn[BNODES], tmp[256];
  const int B = blockIdx.x, t = threadIdx.x;
  const long base = (long)B * CAP_E;
  int m = curD[B]; if (m > CAP_E) m = CAP_E;
  for (int i = t; i < BNODES; i += 256) cnt[i] = 0;
  __syncthreads();
  for (int i = t; i < m; i += 256){
    unsigned p = partD[base + i];
    ed[i] = p;
    atomicAdd(&cnt[p >> 17], 1);
  }
  __syncthreads();
  int a0 = cnt[2 * t], a1 = cnt[2 * t + 1];
  int s = a0 + a1;
  tmp[t] = s;
  __syncthreads();
  for (int off = 1; off < 256; off <<= 1){
    int v = (t >= off) ? tmp[t - off] : 0;
    __syncthreads();
    tmp[t] += v;
    __syncthreads();
  }
  int excl = tmp[t] - s;
  scn[2 * t]     = excl;
  scn[2 * t + 1] = excl + a0;
  __syncthreads();
  const int nodeBase = B << BSHIFT;
  for (int i = t; i < BNODES; i += 256){
    int node = nodeBase + i;
    if (node < N){ rowptr[node] = (int)base + scn[i]; degD[node] = cnt[i]; }
  }
  __syncthreads();
  int* csr = (int*)partD;
  for (int i = t; i < m; i += 256){
    unsigned p = ed[i];
    int slot = atomicAdd(&scn[p >> 17], 1);
    csr[base + slot] = (int)(p & 0x1FFFFu);
  }
  // degS from partS
  int mS = curS[B]; if (mS > CAP_E) mS = CAP_E;
  __syncthreads();
  for (int i = t; i < BNODES; i += 256) cnt[i] = 0;
  __syncthreads();
  for (int i = t; i < mS; i += 256)
    atomicAdd(&cnt[partS[base + i] & (BNODES - 1)], 1);
  __syncthreads();
  for (int i = t; i < BNODES; i += 256){
    int node = nodeBase + i;
    if (node < N) degS[node] = cnt[i];
  }
}

// ---------------- CSR aggregation: one wave per dst node, float4 lanes ----------------
template<int MODE>
__global__ __launch_bounds__(256) void k_agg(const float* __restrict__ h,
    const int* __restrict__ rowptr, const int* __restrict__ degD,
    const int* __restrict__ csr, const float* __restrict__ bias,
    float* __restrict__ out, int N)
{
  int node = blockIdx.x * 4 + (threadIdx.x >> 6);
  if (node >= N) return;
  int lane = threadIdx.x & 63;
  int eg = lane >> 4;
  int c4 = (lane & 15) << 2;
  int beg = rowptr[node];
  int deg = degD[node];
  int end = beg + deg;

  float ax = 0.f, ay = 0.f, az = 0.f, aw = 0.f;
  float bx = 0.f, by = 0.f, bz = 0.f, bw = 0.f;
  int p = beg + eg;
  for (; p + 12 < end; p += 16){
    int s0 = __builtin_nontemporal_load(csr + p);
    int s1 = __builtin_nontemporal_load(csr + p + 4);
    int s2 = __builtin_nontemporal_load(csr + p + 8);
    int s3 = __builtin_nontemporal_load(csr + p + 12);
    float4 v0 = *(const float4*)&h[(long)s0 * 64 + c4];
    float4 v1 = *(const float4*)&h[(long)s1 * 64 + c4];
    float4 v2 = *(const float4*)&h[(long)s2 * 64 + c4];
    float4 v3 = *(const float4*)&h[(long)s3 * 64 + c4];
    ax += v0.x; ay += v0.y; az += v0.z; aw += v0.w;
    bx += v1.x; by += v1.y; bz += v1.z; bw += v1.w;
    ax += v2.x; ay += v2.y; az += v2.z; aw += v2.w;
    bx += v3.x; by += v3.y; bz += v3.z; bw += v3.w;
  }
  for (; p < end; p += 4){
    int s = __builtin_nontemporal_load(csr + p);
    float4 v = *(const float4*)&h[(long)s * 64 + c4];
    ax += v.x; ay += v.y; az += v.z; aw += v.w;
  }
  ax += bx; ay += by; az += bz; aw += bw;

  ax += __shfl_xor(ax, 16); ay += __shfl_xor(ay, 16);
  az += __shfl_xor(az, 16); aw += __shfl_xor(aw, 16);
  ax += __shfl_xor(ax, 32); ay += __shfl_xor(ay, 32);
  az += __shfl_xor(az, 32); aw += __shfl_xor(aw, 32);

  if (eg == 0){
    float4 bb = *(const float4*)&bias[c4];
    f32x4 r;
    if constexpr (MODE == 1){
      float nd = rsqrtf((float)(deg < 1 ? 1 : deg));
      r.x = fmaxf(fmaf(ax, nd, bb.x), 0.f);
      r.y = fmaxf(fmaf(ay, nd, bb.y), 0.f);
      r.z = fmaxf(fmaf(az, nd, bb.z), 0.f);
      r.w = fmaxf(fmaf(aw, nd, bb.w), 0.f);
    } else {
      r.x = ax + bb.x; r.y = ay + bb.y; r.z = az + bb.z; r.w = aw + bb.w;
    }
    __builtin_nontemporal_store(r, (f32x4*)&out[(long)node * 64 + c4]);
  }
}

// ---------------- fp32 GEMM v5: out[N][64] = (A0|A1)[N][K] @ W[K][64] ----------------
// BM=64, BK=64 chunks, 4x4 register tile (VGPR ~80, no cliff).
// LDS = 64*68*4 + 64*64*4 = 33.8 KB -> 4 blocks/CU (16 waves, 50% occ).
// a-reads: broadcast across 16 lanes, 4 ty/wave at f4-stride 17 -> disjoint
// bank quads (conflict-free). w-reads: 16 consecutive f4 -> 2-way (free).
template<int K0, int K1, bool SCALE>
__global__ __launch_bounds__(256) void k_gemm(
    const float* __restrict__ A0, const float* __restrict__ A1,
    const float* __restrict__ W, const int* __restrict__ degS,
    float* __restrict__ out, int N)
{
  constexpr int K   = K0 + K1;
  constexpr int NCH = K / 64;
  constexpr int LDA = 68;
  __shared__ float sA[64 * LDA];   // 17.4 KB
  __shared__ float sW[64 * 64];    // 16.4 KB
  const int tid  = threadIdx.x;
  const int brow = blockIdx.x * 64;
  const int tx = tid & 15, ty = tid >> 4;
  const int c0 = tx << 2;

  float4 acc[4];
  #pragma unroll
  for (int i = 0; i < 4; i++) acc[i] = make_float4(0.f, 0.f, 0.f, 0.f);

  for (int ch = 0; ch < NCH; ++ch){
    if (ch) __syncthreads();
    // W chunk [64][64]: 1024 f4, 4 per thread
    #pragma unroll
    for (int it = 0; it < 4; it++){
      int id = tid + it * 256;
      int k = id >> 4, c4 = (id & 15) << 2;
      *(float4*)&sW[k * 64 + c4] = *(const float4*)&W[(ch * 64 + k) * 64 + c4];
    }
    // A chunk [64][64]: 1024 f4, 4 per thread
    #pragma unroll
    for (int it = 0; it < 4; it++){
      int id = tid + it * 256;
      int r = id >> 4, kk = id & 15;
      int row = brow + r;
      int k = ch * 64 + kk * 4;
      float4 v = make_float4(0.f, 0.f, 0.f, 0.f);
      if (row < N){
        if constexpr (K1 == 0){
          v = *(const float4*)&A0[(long)row * K0 + k];
        } else {
          if (k < K0) v = *(const float4*)&A0[(long)row * K0 + k];
          else        v = *(const float4*)&A1[(long)row * K1 + (k - K0)];
        }
        if constexpr (SCALE){
          int dg = degS[row];
          float s = rsqrtf((float)(dg < 1 ? 1 : dg));
          v.x *= s; v.y *= s; v.z *= s; v.w *= s;
        }
      }
      *(float4*)&sA[r * LDA + kk * 4] = v;
    }
    __syncthreads();
    // compute: 16 kk-steps of K4=4
    #pragma unroll
    for (int kk = 0; kk < 16; ++kk){
      float4 w0 = *(const float4*)&sW[(kk * 4 + 0) * 64 + c0];
      float4 w1 = *(const float4*)&sW[(kk * 4 + 1) * 64 + c0];
      float4 w2 = *(const float4*)&sW[(kk * 4 + 2) * 64 + c0];
      float4 w3 = *(const float4*)&sW[(kk * 4 + 3) * 64 + c0];
      #pragma unroll
      for (int i = 0; i < 4; i++){
        float4 a = *(const float4*)&sA[(ty + 16 * i) * LDA + kk * 4];
        acc[i].x += a.x * w0.x + a.y * w1.x + a.z * w2.x + a.w * w3.x;
        acc[i].y += a.x * w0.y + a.y * w1.y + a.z * w2.y + a.w * w3.y;
        acc[i].z += a.x * w0.z + a.y * w1.z + a.z * w2.z + a.w * w3.z;
        acc[i].w += a.x * w0.w + a.y * w1.w + a.z * w2.w + a.w * w3.w;
      }
    }
  }
  #pragma unroll
  for (int i = 0; i < 4; i++){
    int row = brow + ty + 16 * i;
    if (row < N) *(float4*)&out[(long)row * 64 + c0] = acc[i];
  }
}

// ---------------- padded-atomic fallback (proven R3 path) ----------------

__global__ void k_prep(const int* __restrict__ src, const int* __restrict__ dst,
                       int* __restrict__ degS, int* __restrict__ degD,
                       int* __restrict__ padded, int E){
  int i = blockIdx.x * blockDim.x + threadIdx.x;
  if (i >= E) return;
  int s = src[i], d = dst[i];
  int slot = atomicAdd(&degD[d], 1);
  if (slot < CAP) padded[(long)d * CAP + slot] = s;
  atomicAdd(&degS[s], 1);
}

template<int MODE>
__global__ __launch_bounds__(256) void k_agg_pad(const float* __restrict__ h,
    const int* __restrict__ padded, const int* __restrict__ degD,
    const float* __restrict__ bias, float* __restrict__ out, int N)
{
  int node = blockIdx.x * 4 + (threadIdx.x >> 6);
  if (node >= N) return;
  int lane = threadIdx.x & 63;
  int deg = degD[node];
  int len = deg < CAP ? deg : CAP;
  const int* row = padded + (long)node * CAP;
  int sid = (lane < len) ? row[lane] : 0;
  float acc0 = 0.f, acc1 = 0.f;
  int t = 0;
  for (; t + 4 <= len; t += 4){
    int s0 = __shfl(sid, t),   s1 = __shfl(sid, t+1);
    int s2 = __shfl(sid, t+2), s3 = __shfl(sid, t+3);
    acc0 += h[(long)s0 * 64 + lane];
    acc1 += h[(long)s1 * 64 + lane];
    acc0 += h[(long)s2 * 64 + lane];
    acc1 += h[(long)s3 * 64 + lane];
  }
  for (; t < len; ++t){
    int s = __shfl(sid, t);
    acc0 += h[(long)s * 64 + lane];
  }
  float acc = acc0 + acc1;
  float r;
  if constexpr (MODE == 1){
    float nd = rsqrtf((float)(deg < 1 ? 1 : deg));
    r = fmaxf(fmaf(acc, nd, bias[lane]), 0.f);
  } else {
    r = acc + bias[lane];
  }
  out[(long)node * 64 + lane] = r;
}

// ---------------- launch ----------------

extern "C" void kernel_launch(void* const* d_in, const int* in_sizes, int n_in,
                              void* d_out, int out_size, void* d_ws, size_t ws_size,
                              hipStream_t stream){
  const float* feats = (const float*)d_in[0];
  const int*   src   = (const int*)  d_in[1];
  const int*   dst   = (const int*)  d_in[2];
  const float* W1    = (const float*)d_in[3];
  const float* b1    = (const float*)d_in[4];
  const float* W2    = (const float*)d_in[5];
  const float* b2    = (const float*)d_in[6];
  const float* Wout  = (const float*)d_in[7];
  const float* bout  = (const float*)d_in[8];
  float* out = (float*)d_out;

  const int N = in_sizes[0] / 128;
  const int E = in_sizes[1];

  const int gemmGrid = divup(N, 64);
  const int aggGrid  = divup(N, 4);
  const int nb       = divup(N, BNODES);

  // ---------- padded-bucket path ----------
  size_t needA = ((size_t)(3L * N) + 512                // degS, degD, rowptr, cursors
                + 2L * (size_t)nb * CAP_E               // partD (->csr in place), partS
                + 192L * N) * 4;                        // ht, h1, h2
  if (N <= 131072 && nb <= 256 && ws_size >= needA){
    int*      degS   = (int*)d_ws;                     // N
    int*      degD   = degS + N;                       // N
    int*      rowptr = degD + N;                       // N
    int*      curD   = rowptr + N;                     // 256
    int*      curS   = curD + 256;                     // 256
    unsigned* partD  = (unsigned*)(curS + 256);        // nb*CAP_E (becomes csr)
    int*      partS  = (int*)(partD + (long)nb * CAP_E); // nb*CAP_E
    float*    ht     = (float*)(partS + (long)nb * CAP_E); // 64N
    float*    h1     = ht + 64L * N;                   // 64N
    float*    h2     = h1 + 64L * N;                   // 64N
    int*      csr    = (int*)partD;

    k_zero32<<<1, 256, 0, stream>>>((unsigned*)curD, 512);
    k_part2<<<PBLK, 256, 0, stream>>>(src, dst, E, divup(E, PBLK), curD, curS, partD, partS);
    k_csr_degs<<<nb, 256, 0, stream>>>(curD, curS, partD, partS, rowptr, degD, degS, N);

    k_gemm<128, 0, true><<<gemmGrid, 256, 0, stream>>>(feats, nullptr, W1, degS, ht, N);
    k_agg<1><<<aggGrid, 256, 0, stream>>>(ht, rowptr, degD, csr, b1, h1, N);

    k_gemm<64, 0, true><<<gemmGrid, 256, 0, stream>>>(h1, nullptr, W2, degS, ht, N);
    k_agg<1><<<aggGrid, 256, 0, stream>>>(ht, rowptr, degD, csr, b2, h2, N);

    k_gemm<64, 64, false><<<gemmGrid, 256, 0, stream>>>(h1, h2, Wout, nullptr, ht, N);
    k_agg<0><<<aggGrid, 256, 0, stream>>>(ht, rowptr, degD, csr, bout, out, N);
    return;
  }

  // ---------- padded-atomic fallback ----------
  int*   degS   = (int*)d_ws;
  int*   degD   = degS + N;
  int*   padded = degD + N;
  float* ht     = (float*)(padded + (long)CAP * N);
  float* h1     = ht + 64L * N;
  float* h2     = h1 + 64L * N;

  k_zero32<<<256, 256, 0, stream>>>((unsigned*)degS, 2L * N);
  k_prep<<<divup(E, 256), 256, 0, stream>>>(src, dst, degS, degD, padded, E);

  k_gemm<128, 0, true><<<gemmGrid, 256, 0, stream>>>(feats, nullptr, W1, degS, ht, N);
  k_agg_pad<1><<<aggGrid, 256, 0, stream>>>(ht, padded, degD, b1, h1, N);

  k_gemm<64, 0, true><<<gemmGrid, 256, 0, stream>>>(h1, nullptr, W2, degS, ht, N);
  k_agg_pad<1><<<aggGrid, 256, 0, stream>>>(ht, padded, degD, b2, h2, N);

  k_gemm<64, 64, false><<<gemmGrid, 256, 0, stream>>>(h1, h2, Wout, nullptr, ht, N);
  k_agg_pad<0><<<aggGrid, 256, 0, stream>>>(ht, padded, degD, bout, out, N);
}

// Round 12
// 355.393 us; speedup vs baseline: 1.2587x; 1.2587x over previous
//
#include <hip/hip_runtime.h>

static inline int divup(long a, long b){ return (int)((a + b - 1) / b); }

typedef float f32x4 __attribute__((ext_vector_type(4)));

#define CAP    64      // padded fallback: slots per dst node
#define BSHIFT 9       // 512 nodes per bucket
#define BNODES 512
#define CAP_E  12288   // fixed per-bucket region (mean ~8163, 29+ sigma headroom)
#define PBLK   256     // partition blocks

// ---------------- utility ----------------

__global__ void k_zero32(unsigned* __restrict__ p, long n){
  long i = (long)blockIdx.x * blockDim.x + threadIdx.x;
  long st = (long)gridDim.x * blockDim.x;
  for (; i < n; i += st) p[i] = 0u;
}

// ---------------- prep: direct padded-bucket partition ----------------
__global__ __launch_bounds__(256) void k_part2(const int* __restrict__ src,
    const int* __restrict__ dst, int E, int per,
    int* __restrict__ curD, int* __restrict__ curS,
    unsigned* __restrict__ partD, int* __restrict__ partS)
{
  __shared__ int hD[256], hS[256];
  const int t = threadIdx.x;
  const int b0 = blockIdx.x * per, b1 = min(E, b0 + per);
  hD[t] = 0; hS[t] = 0;
  __syncthreads();
  for (int i = b0 + t; i < b1; i += 256){
    atomicAdd(&hD[dst[i] >> BSHIFT], 1);
    atomicAdd(&hS[src[i] >> BSHIFT], 1);
  }
  __syncthreads();
  { int c = hD[t]; hD[t] = c ? atomicAdd(&curD[t], c) : 0;
    c = hS[t];     hS[t] = c ? atomicAdd(&curS[t], c) : 0; }
  __syncthreads();
  for (int i = b0 + t; i < b1; i += 256){
    int s = src[i], d = dst[i];
    int bD = d >> BSHIFT;
    int p = atomicAdd(&hD[bD], 1);
    if (p < CAP_E)
      partD[(long)bD * CAP_E + p] = ((unsigned)(d & (BNODES - 1)) << 17) | (unsigned)s;
    int bS = s >> BSHIFT;
    int q = atomicAdd(&hS[bS], 1);
    if (q < CAP_E)
      partS[(long)bS * CAP_E + q] = s;
  }
}

// per-bucket LDS counting sort IN PLACE (csr overwrites partD) -> rowptr,
// degD; then degS histogram from partS. One block per bucket.
__global__ __launch_bounds__(256) void k_csr_degs(const int* __restrict__ curD,
    const int* __restrict__ curS, unsigned* __restrict__ partD,
    const int* __restrict__ partS, int* __restrict__ rowptr,
    int* __restrict__ degD, int* __restrict__ degS, int N)
{
  __shared__ unsigned ed[CAP_E];          // 48 KB
  __shared__ int cnt[BNODES], scn[BNODES], tmp[256];
  const int B = blockIdx.x, t = threadIdx.x;
  const long base = (long)B * CAP_E;
  int m = curD[B]; if (m > CAP_E) m = CAP_E;
  for (int i = t; i < BNODES; i += 256) cnt[i] = 0;
  __syncthreads();
  for (int i = t; i < m; i += 256){
    unsigned p = partD[base + i];
    ed[i] = p;
    atomicAdd(&cnt[p >> 17], 1);
  }
  __syncthreads();
  int a0 = cnt[2 * t], a1 = cnt[2 * t + 1];
  int s = a0 + a1;
  tmp[t] = s;
  __syncthreads();
  for (int off = 1; off < 256; off <<= 1){
    int v = (t >= off) ? tmp[t - off] : 0;
    __syncthreads();
    tmp[t] += v;
    __syncthreads();
  }
  int excl = tmp[t] - s;
  scn[2 * t]     = excl;
  scn[2 * t + 1] = excl + a0;
  __syncthreads();
  const int nodeBase = B << BSHIFT;
  for (int i = t; i < BNODES; i += 256){
    int node = nodeBase + i;
    if (node < N){ rowptr[node] = (int)base + scn[i]; degD[node] = cnt[i]; }
  }
  __syncthreads();
  int* csr = (int*)partD;
  for (int i = t; i < m; i += 256){
    unsigned p = ed[i];
    int slot = atomicAdd(&scn[p >> 17], 1);
    csr[base + slot] = (int)(p & 0x1FFFFu);
  }
  // degS from partS
  int mS = curS[B]; if (mS > CAP_E) mS = CAP_E;
  __syncthreads();
  for (int i = t; i < BNODES; i += 256) cnt[i] = 0;
  __syncthreads();
  for (int i = t; i < mS; i += 256)
    atomicAdd(&cnt[partS[base + i] & (BNODES - 1)], 1);
  __syncthreads();
  for (int i = t; i < BNODES; i += 256){
    int node = nodeBase + i;
    if (node < N) degS[node] = cnt[i];
  }
}

// ---------------- CSR aggregation: one wave per dst node, float4 lanes ----------------
template<int MODE>
__global__ __launch_bounds__(256) void k_agg(const float* __restrict__ h,
    const int* __restrict__ rowptr, const int* __restrict__ degD,
    const int* __restrict__ csr, const float* __restrict__ bias,
    float* __restrict__ out, int N)
{
  int node = blockIdx.x * 4 + (threadIdx.x >> 6);
  if (node >= N) return;
  int lane = threadIdx.x & 63;
  int eg = lane >> 4;
  int c4 = (lane & 15) << 2;
  int beg = rowptr[node];
  int deg = degD[node];
  int end = beg + deg;

  float ax = 0.f, ay = 0.f, az = 0.f, aw = 0.f;
  float bx = 0.f, by = 0.f, bz = 0.f, bw = 0.f;
  int p = beg + eg;
  for (; p + 12 < end; p += 16){
    int s0 = __builtin_nontemporal_load(csr + p);
    int s1 = __builtin_nontemporal_load(csr + p + 4);
    int s2 = __builtin_nontemporal_load(csr + p + 8);
    int s3 = __builtin_nontemporal_load(csr + p + 12);
    float4 v0 = *(const float4*)&h[(long)s0 * 64 + c4];
    float4 v1 = *(const float4*)&h[(long)s1 * 64 + c4];
    float4 v2 = *(const float4*)&h[(long)s2 * 64 + c4];
    float4 v3 = *(const float4*)&h[(long)s3 * 64 + c4];
    ax += v0.x; ay += v0.y; az += v0.z; aw += v0.w;
    bx += v1.x; by += v1.y; bz += v1.z; bw += v1.w;
    ax += v2.x; ay += v2.y; az += v2.z; aw += v2.w;
    bx += v3.x; by += v3.y; bz += v3.z; bw += v3.w;
  }
  for (; p < end; p += 4){
    int s = __builtin_nontemporal_load(csr + p);
    float4 v = *(const float4*)&h[(long)s * 64 + c4];
    ax += v.x; ay += v.y; az += v.z; aw += v.w;
  }
  ax += bx; ay += by; az += bz; aw += bw;

  ax += __shfl_xor(ax, 16); ay += __shfl_xor(ay, 16);
  az += __shfl_xor(az, 16); aw += __shfl_xor(aw, 16);
  ax += __shfl_xor(ax, 32); ay += __shfl_xor(ay, 32);
  az += __shfl_xor(az, 32); aw += __shfl_xor(aw, 32);

  if (eg == 0){
    float4 bb = *(const float4*)&bias[c4];
    f32x4 r;
    if constexpr (MODE == 1){
      float nd = rsqrtf((float)(deg < 1 ? 1 : deg));
      r.x = fmaxf(fmaf(ax, nd, bb.x), 0.f);
      r.y = fmaxf(fmaf(ay, nd, bb.y), 0.f);
      r.z = fmaxf(fmaf(az, nd, bb.z), 0.f);
      r.w = fmaxf(fmaf(aw, nd, bb.w), 0.f);
    } else {
      r.x = ax + bb.x; r.y = ay + bb.y; r.z = az + bb.z; r.w = aw + bb.w;
    }
    __builtin_nontemporal_store(r, (f32x4*)&out[(long)node * 64 + c4]);
  }
}

// ---------------- fp32 GEMM v6: out[N][64] = (A0|A1)[N][K] @ W[K][64] ----------------
// Only W is staged in LDS (16-32 KB, one sync). A is streamed from global:
// the 16 lanes sharing a row issue IDENTICAL addresses (HW broadcast), so
// each row is fetched once per block via L1/L2 and loads pipeline directly
// into the FMA stream (no stage->sync->compute ping-pong). Row scale
// (rsqrt(deg)) commutes with the GEMM -> applied in the epilogue.
// BM=64, 4x4 per-thread tile. LDS 32 KB (K=128) / 16 KB (K=64).
template<int K0, int K1, bool SCALE>
__global__ __launch_bounds__(256) void k_gemm(
    const float* __restrict__ A0, const float* __restrict__ A1,
    const float* __restrict__ W, const int* __restrict__ degS,
    float* __restrict__ out, int N)
{
  constexpr int K = K0 + K1;
  __shared__ float sW[K * 64];
  const int tid  = threadIdx.x;
  const int brow = blockIdx.x * 64;
  const int tx = tid & 15, ty = tid >> 4;
  const int c0 = tx << 2;

  // stage W [K][64]
  #pragma unroll
  for (int it = 0; it < K / 16; it++){
    int id = tid + it * 256;
    int k = id >> 4, c4 = (id & 15) << 2;
    *(float4*)&sW[k * 64 + c4] = *(const float4*)&W[k * 64 + c4];
  }

  // row pointers (clamp OOB rows to row 0; store is guarded)
  const float* pa0[4];
  const float* pa1[4];
  float scale[4];
  #pragma unroll
  for (int i = 0; i < 4; i++){
    int row = brow + ty + 16 * i;
    int r = (row < N) ? row : 0;
    pa0[i] = A0 + (long)r * K0;
    if constexpr (K1 != 0) pa1[i] = A1 + (long)r * K1;
    if constexpr (SCALE){
      int dg = degS[r];
      scale[i] = rsqrtf((float)(dg < 1 ? 1 : dg));
    }
  }

  __syncthreads();

  float4 acc[4];
  #pragma unroll
  for (int i = 0; i < 4; i++) acc[i] = make_float4(0.f, 0.f, 0.f, 0.f);

  #pragma unroll 2
  for (int kk = 0; kk < K0 / 4; ++kk){
    float4 a[4];
    #pragma unroll
    for (int i = 0; i < 4; i++) a[i] = *(const float4*)&pa0[i][kk * 4];
    float4 w0 = *(const float4*)&sW[(4 * kk + 0) * 64 + c0];
    float4 w1 = *(const float4*)&sW[(4 * kk + 1) * 64 + c0];
    float4 w2 = *(const float4*)&sW[(4 * kk + 2) * 64 + c0];
    float4 w3 = *(const float4*)&sW[(4 * kk + 3) * 64 + c0];
    #pragma unroll
    for (int i = 0; i < 4; i++){
      acc[i].x += a[i].x * w0.x + a[i].y * w1.x + a[i].z * w2.x + a[i].w * w3.x;
      acc[i].y += a[i].x * w0.y + a[i].y * w1.y + a[i].z * w2.y + a[i].w * w3.y;
      acc[i].z += a[i].x * w0.z + a[i].y * w1.z + a[i].z * w2.z + a[i].w * w3.z;
      acc[i].w += a[i].x * w0.w + a[i].y * w1.w + a[i].z * w2.w + a[i].w * w3.w;
    }
  }
  if constexpr (K1 != 0){
    #pragma unroll 2
    for (int kk = 0; kk < K1 / 4; ++kk){
      float4 a[4];
      #pragma unroll
      for (int i = 0; i < 4; i++) a[i] = *(const float4*)&pa1[i][kk * 4];
      int kb = K0 + 4 * kk;
      float4 w0 = *(const float4*)&sW[(kb + 0) * 64 + c0];
      float4 w1 = *(const float4*)&sW[(kb + 1) * 64 + c0];
      float4 w2 = *(const float4*)&sW[(kb + 2) * 64 + c0];
      float4 w3 = *(const float4*)&sW[(kb + 3) * 64 + c0];
      #pragma unroll
      for (int i = 0; i < 4; i++){
        acc[i].x += a[i].x * w0.x + a[i].y * w1.x + a[i].z * w2.x + a[i].w * w3.x;
        acc[i].y += a[i].x * w0.y + a[i].y * w1.y + a[i].z * w2.y + a[i].w * w3.y;
        acc[i].z += a[i].x * w0.z + a[i].y * w1.z + a[i].z * w2.z + a[i].w * w3.z;
        acc[i].w += a[i].x * w0.w + a[i].y * w1.w + a[i].z * w2.w + a[i].w * w3.w;
      }
    }
  }

  #pragma unroll
  for (int i = 0; i < 4; i++){
    int row = brow + ty + 16 * i;
    if (row < N){
      f32x4 r;
      if constexpr (SCALE){
        r.x = acc[i].x * scale[i]; r.y = acc[i].y * scale[i];
        r.z = acc[i].z * scale[i]; r.w = acc[i].w * scale[i];
      } else {
        r.x = acc[i].x; r.y = acc[i].y; r.z = acc[i].z; r.w = acc[i].w;
      }
      *(f32x4*)&out[(long)row * 64 + c0] = r;
    }
  }
}

// ---------------- padded-atomic fallback (proven R3 path) ----------------

__global__ void k_prep(const int* __restrict__ src, const int* __restrict__ dst,
                       int* __restrict__ degS, int* __restrict__ degD,
                       int* __restrict__ padded, int E){
  int i = blockIdx.x * blockDim.x + threadIdx.x;
  if (i >= E) return;
  int s = src[i], d = dst[i];
  int slot = atomicAdd(&degD[d], 1);
  if (slot < CAP) padded[(long)d * CAP + slot] = s;
  atomicAdd(&degS[s], 1);
}

template<int MODE>
__global__ __launch_bounds__(256) void k_agg_pad(const float* __restrict__ h,
    const int* __restrict__ padded, const int* __restrict__ degD,
    const float* __restrict__ bias, float* __restrict__ out, int N)
{
  int node = blockIdx.x * 4 + (threadIdx.x >> 6);
  if (node >= N) return;
  int lane = threadIdx.x & 63;
  int deg = degD[node];
  int len = deg < CAP ? deg : CAP;
  const int* row = padded + (long)node * CAP;
  int sid = (lane < len) ? row[lane] : 0;
  float acc0 = 0.f, acc1 = 0.f;
  int t = 0;
  for (; t + 4 <= len; t += 4){
    int s0 = __shfl(sid, t),   s1 = __shfl(sid, t+1);
    int s2 = __shfl(sid, t+2), s3 = __shfl(sid, t+3);
    acc0 += h[(long)s0 * 64 + lane];
    acc1 += h[(long)s1 * 64 + lane];
    acc0 += h[(long)s2 * 64 + lane];
    acc1 += h[(long)s3 * 64 + lane];
  }
  for (; t < len; ++t){
    int s = __shfl(sid, t);
    acc0 += h[(long)s * 64 + lane];
  }
  float acc = acc0 + acc1;
  float r;
  if constexpr (MODE == 1){
    float nd = rsqrtf((float)(deg < 1 ? 1 : deg));
    r = fmaxf(fmaf(acc, nd, bias[lane]), 0.f);
  } else {
    r = acc + bias[lane];
  }
  out[(long)node * 64 + lane] = r;
}

// ---------------- launch ----------------

extern "C" void kernel_launch(void* const* d_in, const int* in_sizes, int n_in,
                              void* d_out, int out_size, void* d_ws, size_t ws_size,
                              hipStream_t stream){
  const float* feats = (const float*)d_in[0];
  const int*   src   = (const int*)  d_in[1];
  const int*   dst   = (const int*)  d_in[2];
  const float* W1    = (const float*)d_in[3];
  const float* b1    = (const float*)d_in[4];
  const float* W2    = (const float*)d_in[5];
  const float* b2    = (const float*)d_in[6];
  const float* Wout  = (const float*)d_in[7];
  const float* bout  = (const float*)d_in[8];
  float* out = (float*)d_out;

  const int N = in_sizes[0] / 128;
  const int E = in_sizes[1];

  const int gemmGrid = divup(N, 64);
  const int aggGrid  = divup(N, 4);
  const int nb       = divup(N, BNODES);

  // ---------- padded-bucket path ----------
  size_t needA = ((size_t)(3L * N) + 512                // degS, degD, rowptr, cursors
                + 2L * (size_t)nb * CAP_E               // partD (->csr in place), partS
                + 192L * N) * 4;                        // ht, h1, h2
  if (N <= 131072 && nb <= 256 && ws_size >= needA){
    int*      degS   = (int*)d_ws;                     // N
    int*      degD   = degS + N;                       // N
    int*      rowptr = degD + N;                       // N
    int*      curD   = rowptr + N;                     // 256
    int*      curS   = curD + 256;                     // 256
    unsigned* partD  = (unsigned*)(curS + 256);        // nb*CAP_E (becomes csr)
    int*      partS  = (int*)(partD + (long)nb * CAP_E); // nb*CAP_E
    float*    ht     = (float*)(partS + (long)nb * CAP_E); // 64N
    float*    h1     = ht + 64L * N;                   // 64N
    float*    h2     = h1 + 64L * N;                   // 64N
    int*      csr    = (int*)partD;

    k_zero32<<<1, 256, 0, stream>>>((unsigned*)curD, 512);
    k_part2<<<PBLK, 256, 0, stream>>>(src, dst, E, divup(E, PBLK), curD, curS, partD, partS);
    k_csr_degs<<<nb, 256, 0, stream>>>(curD, curS, partD, partS, rowptr, degD, degS, N);

    k_gemm<128, 0, true><<<gemmGrid, 256, 0, stream>>>(feats, nullptr, W1, degS, ht, N);
    k_agg<1><<<aggGrid, 256, 0, stream>>>(ht, rowptr, degD, csr, b1, h1, N);

    k_gemm<64, 0, true><<<gemmGrid, 256, 0, stream>>>(h1, nullptr, W2, degS, ht, N);
    k_agg<1><<<aggGrid, 256, 0, stream>>>(ht, rowptr, degD, csr, b2, h2, N);

    k_gemm<64, 64, false><<<gemmGrid, 256, 0, stream>>>(h1, h2, Wout, nullptr, ht, N);
    k_agg<0><<<aggGrid, 256, 0, stream>>>(ht, rowptr, degD, csr, bout, out, N);
    return;
  }

  // ---------- padded-atomic fallback ----------
  int*   degS   = (int*)d_ws;
  int*   degD   = degS + N;
  int*   padded = degD + N;
  float* ht     = (float*)(padded + (long)CAP * N);
  float* h1     = ht + 64L * N;
  float* h2     = h1 + 64L * N;

  k_zero32<<<256, 256, 0, stream>>>((unsigned*)degS, 2L * N);
  k_prep<<<divup(E, 256), 256, 0, stream>>>(src, dst, degS, degD, padded, E);

  k_gemm<128, 0, true><<<gemmGrid, 256, 0, stream>>>(feats, nullptr, W1, degS, ht, N);
  k_agg_pad<1><<<aggGrid, 256, 0, stream>>>(ht, padded, degD, b1, h1, N);

  k_gemm<64, 0, true><<<gemmGrid, 256, 0, stream>>>(h1, nullptr, W2, degS, ht, N);
  k_agg_pad<1><<<aggGrid, 256, 0, stream>>>(ht, padded, degD, b2, h2, N);

  k_gemm<64, 64, false><<<gemmGrid, 256, 0, stream>>>(h1, h2, Wout, nullptr, ht, N);
  k_agg_pad<0><<<aggGrid, 256, 0, stream>>>(ht, padded, degD, bout, out, N);
}